// Round 10
// baseline (583.531 us; speedup 1.0000x reference)
//
#include <hip/hip_runtime.h>
#include <hip/hip_bf16.h>

#define NN 100000
#define NE 800000
// D=128, H=4, C=32

typedef __attribute__((ext_vector_type(8))) short bf16x8;
typedef __attribute__((ext_vector_type(4))) float f32x4;
typedef unsigned short ushort_t;

static __device__ __forceinline__ short f2bf(float f) {
    union { float f; unsigned u; } v; v.f = f;
    unsigned u = v.u;
    unsigned r = u + 0x7FFFu + ((u >> 16) & 1u);   // RNE
    return (short)(r >> 16);
}
static __device__ __forceinline__ float bf2f(unsigned short u) {
    union { unsigned u; float f; } v; v.u = ((unsigned)u) << 16;
    return v.f;
}

// ---------------- weight prep: W[k][c] fp32 -> Wt[c][k] bf16, 9 matrices ------------
__global__ void prep_w_k(const float* __restrict__ w_in, const float* __restrict__ Wl,
                         const float* __restrict__ Wr, const float* __restrict__ Wres,
                         ushort_t* __restrict__ wt)
{
    __shared__ float tile[32][33];
    int m = blockIdx.z;
    const float* src;
    if (m == 0)      src = w_in;
    else if (m < 4)  src = Wl + (size_t)(m - 1) * 16384;
    else if (m < 7)  src = Wr + (size_t)(m - 4) * 16384;
    else             src = Wres + (size_t)(m - 7) * 16384;
    ushort_t* dst = wt + (size_t)m * 16384;

    int tx = threadIdx.x, ty = threadIdx.y;
    int k0 = blockIdx.x * 32, c0 = blockIdx.y * 32;
    #pragma unroll
    for (int j = 0; j < 4; ++j)
        tile[ty + 8 * j][tx] = src[(size_t)(k0 + ty + 8 * j) * 128 + c0 + tx];
    __syncthreads();
    #pragma unroll
    for (int j = 0; j < 4; ++j)
        dst[(size_t)(c0 + ty + 8 * j) * 128 + k0 + tx] = (ushort_t)f2bf(tile[tx][ty + 8 * j]);
}

// ---------------- GEMM: 128-row tiles, B-tile staged dense in LDS ----------------
// out = A[M x 128] @ wt[w_y]^T + bias; y-slices run concurrently sharing A via L2.
// OPERAND-SWAPPED MFMA: mfma(b, afr) computes the transposed fragment, so each lane
// holds output row = lr, cols = nt*16 + quad*4 + {0..3} — 4 CONSECUTIVE columns.
// Epilogue: bias (float4) + 2x v_cvt_pk_bf16_f32 + one 8B store per (mt,nt).
// Replaces the old ~280-instr LDS C-tile transpose (64 scalar ds_writes + 2 barriers).
template<int A_FP32>
__global__ __launch_bounds__(256, 4)
void gemm_k(const void* __restrict__ Av, const ushort_t* __restrict__ wt,
            int w0, int w1, int w2,
            const float* __restrict__ bias0, const float* __restrict__ bias2,
            ushort_t* __restrict__ out0, int Dout0, ushort_t* __restrict__ out2, int M)
{
    __shared__ short Bs[128][136];   // B-tile [col][k]
    const int tid = threadIdx.x;
    const int rowBlk = blockIdx.x * 128;
    const int y = blockIdx.y;
    const ushort_t* W = wt + (size_t)((y == 0) ? w0 : (y == 1) ? w1 : w2) * 16384;
    const float* bias = (y == 0) ? bias0 : ((y == 2) ? bias2 : nullptr);
    ushort_t* out = (y == 2) ? out2 : out0;
    const int Dout   = (y == 2) ? 128 : Dout0;
    const int colOff = (y == 1) ? 128 : 0;

    const int wave = tid >> 6;
    const int lane = tid & 63;
    const int quad = lane >> 4;
    const int lr   = lane & 15;

    const int row0 = rowBlk + wave * 32 + lr;       // A fragment rows
    const int row1 = row0 + 16;

    // ---- A fragments direct from global (issued first, latency-hidden) ----
    bf16x8 afr[4][2];
    #pragma unroll
    for (int ks = 0; ks < 4; ++ks) {
        int kb = ks * 32 + quad * 8;
        bf16x8 a0 = (bf16x8)0, a1 = (bf16x8)0;
        if (A_FP32) {
            const float* A = (const float*)Av;
            if (row0 < M) {
                float4 v0 = *(const float4*)(A + (size_t)row0 * 128 + kb);
                float4 v1 = *(const float4*)(A + (size_t)row0 * 128 + kb + 4);
                a0[0]=f2bf(v0.x); a0[1]=f2bf(v0.y); a0[2]=f2bf(v0.z); a0[3]=f2bf(v0.w);
                a0[4]=f2bf(v1.x); a0[5]=f2bf(v1.y); a0[6]=f2bf(v1.z); a0[7]=f2bf(v1.w);
            }
            if (row1 < M) {
                float4 v0 = *(const float4*)(A + (size_t)row1 * 128 + kb);
                float4 v1 = *(const float4*)(A + (size_t)row1 * 128 + kb + 4);
                a1[0]=f2bf(v0.x); a1[1]=f2bf(v0.y); a1[2]=f2bf(v0.z); a1[3]=f2bf(v0.w);
                a1[4]=f2bf(v1.x); a1[5]=f2bf(v1.y); a1[6]=f2bf(v1.z); a1[7]=f2bf(v1.w);
            }
        } else {
            const ushort_t* A = (const ushort_t*)Av;
            if (row0 < M) a0 = *(const bf16x8*)(A + (size_t)row0 * 128 + kb);
            if (row1 < M) a1 = *(const bf16x8*)(A + (size_t)row1 * 128 + kb);
        }
        afr[ks][0] = a0; afr[ks][1] = a1;
    }

    // ---- stage B-tile densely: global 16B/lane contiguous -> LDS rows ----
    #pragma unroll
    for (int i = 0; i < 8; ++i) {
        int linear = tid + 256 * i;              // 2048 16B chunks
        int r  = linear >> 4;
        int c8 = (linear & 15) << 3;
        *(bf16x8*)&Bs[r][c8] = *(const bf16x8*)(W + (size_t)r * 128 + c8);
    }
    __syncthreads();

    f32x4 acc[2][8];
    #pragma unroll
    for (int mt = 0; mt < 2; ++mt)
        #pragma unroll
        for (int nt = 0; nt < 8; ++nt) acc[mt][nt] = (f32x4)(0.0f);

    #pragma unroll
    for (int ks = 0; ks < 4; ++ks) {
        int kb = ks * 32 + quad * 8;
        #pragma unroll
        for (int nt = 0; nt < 8; ++nt) {
            bf16x8 b = *(const bf16x8*)&Bs[nt * 16 + lr][kb];
            // swapped operands: D = Wt-frag · A-frag^T  ->  lane holds
            // out[row = ...+lr][col = nt*16 + quad*4 + reg]
            acc[0][nt] = __builtin_amdgcn_mfma_f32_16x16x32_bf16(b, afr[ks][0], acc[0][nt], 0, 0, 0);
            acc[1][nt] = __builtin_amdgcn_mfma_f32_16x16x32_bf16(b, afr[ks][1], acc[1][nt], 0, 0, 0);
        }
    }

    // ---- epilogue: register-direct stores, 8B per (mt,nt) per lane ----
    #pragma unroll
    for (int nt = 0; nt < 8; ++nt) {
        int colBase = nt * 16 + quad * 4;
        float4 bv;
        if (bias) bv = *(const float4*)(bias + colBase);
        else { bv.x = 0.f; bv.y = 0.f; bv.z = 0.f; bv.w = 0.f; }
        #pragma unroll
        for (int mt = 0; mt < 2; ++mt) {
            int gr = rowBlk + wave * 32 + mt * 16 + lr;
            if (gr < M) {
                float y0 = acc[mt][nt][0] + bv.x, y1 = acc[mt][nt][1] + bv.y;
                float y2 = acc[mt][nt][2] + bv.z, y3 = acc[mt][nt][3] + bv.w;
                unsigned lo, hi;
                asm("v_cvt_pk_bf16_f32 %0, %1, %2" : "=v"(lo) : "v"(y0), "v"(y1));
                asm("v_cvt_pk_bf16_f32 %0, %1, %2" : "=v"(hi) : "v"(y2), "v"(y3));
                uint2 o; o.x = lo; o.y = hi;
                *(uint2*)(out + (size_t)gr * Dout + colOff + colBase) = o;
            }
        }
    }
}

// ---------------- CSR build ----------------
__global__ void count_k(const int* __restrict__ dst, int* __restrict__ deg) {
    int e = blockIdx.x * 256 + threadIdx.x;
    if (e < NE) atomicAdd(&deg[dst[e]], 1);
}

__global__ void scan1_k(const int* __restrict__ deg, int* __restrict__ excl,
                        int* __restrict__ bsum) {
    __shared__ int buf[256];
    int i = blockIdx.x * 256 + threadIdx.x;
    int v = (i < NN) ? deg[i] : 0;
    buf[threadIdx.x] = v; __syncthreads();
    for (int off = 1; off < 256; off <<= 1) {
        int t = (threadIdx.x >= off) ? buf[threadIdx.x - off] : 0;
        __syncthreads();
        buf[threadIdx.x] += t;
        __syncthreads();
    }
    if (i < NN) excl[i] = buf[threadIdx.x] - v;
    if (threadIdx.x == 255) bsum[blockIdx.x] = buf[255];
}

__global__ void scan2_k(int* __restrict__ bsum, int nb, int* __restrict__ total) {
    __shared__ int buf[512];
    int v = (threadIdx.x < nb) ? bsum[threadIdx.x] : 0;
    buf[threadIdx.x] = v; __syncthreads();
    for (int off = 1; off < 512; off <<= 1) {
        int t = (threadIdx.x >= off) ? buf[threadIdx.x - off] : 0;
        __syncthreads();
        buf[threadIdx.x] += t;
        __syncthreads();
    }
    if (threadIdx.x < nb) bsum[threadIdx.x] = buf[threadIdx.x] - v;  // exclusive base
    if (threadIdx.x == 511) *total = buf[511];
}

__global__ void scan3_k(int* __restrict__ row_ptr, const int* __restrict__ bsum,
                        int* __restrict__ cursor) {
    int i = blockIdx.x * 256 + threadIdx.x;
    if (i < NN) {
        int v = row_ptr[i] + bsum[blockIdx.x];
        row_ptr[i] = v;
        cursor[i]  = v;
    }
}

__global__ void scatter_k(const int* __restrict__ src, const int* __restrict__ dst,
                          int* __restrict__ cursor, int* __restrict__ csr_src) {
    int e = blockIdx.x * 256 + threadIdx.x;
    if (e < NE) {
        int p = atomicAdd(&cursor[dst[e]], 1);
        csr_src[p] = src[e];
    }
}

// ---------------- GATv2 aggregate: one wave per destination node, 8 edges/iter --------
// R9 form (best measured): prefetched csr indices, abs-decomposed logit in log2 domain.
__global__ __launch_bounds__(256, 8)
void gat_aggregate_k(const ushort_t* __restrict__ xlr, const int* __restrict__ row_ptr,
                     const int* __restrict__ csr_src, const float* __restrict__ att,
                     const float* __restrict__ b_out, ushort_t* __restrict__ g)
{
    int node = blockIdx.x * 4 + (threadIdx.x >> 6);
    int lane = threadIdx.x & 63;
    int slot = lane >> 4;
    int cl   = (lane & 15) << 3;                 // channels cl..cl+7
    bf16x8 xru = *(const bf16x8*)(xlr + (size_t)node * 256 + 128 + cl);
    float xr[8], at4[8];
    #pragma unroll
    for (int j = 0; j < 8; ++j) xr[j] = bf2f((ushort_t)xru[j]);
    const float k4 = 0.4f * 1.44269504f;         // 0.4 * log2(e)
    float4 at0 = *(const float4*)(att + cl);
    float4 at1 = *(const float4*)(att + cl + 4);
    at4[0] = k4*at0.x; at4[1] = k4*at0.y; at4[2] = k4*at0.z; at4[3] = k4*at0.w;
    at4[4] = k4*at1.x; at4[5] = k4*at1.y; at4[6] = k4*at1.z; at4[7] = k4*at1.w;

    int e0 = row_ptr[node], e1 = row_ptr[node + 1];
    float acc[8] = {0.f,0.f,0.f,0.f,0.f,0.f,0.f,0.f};
    float suma = 0.f;

    // prime the index pipeline (guard deg==0 nodes: never read past csr_src[e1-1])
    int sa = 0, sb = 0;
    if (e0 < e1) {
        int ea = e0 + slot, eb = e0 + 4 + slot;
        sa = csr_src[ea < e1 ? ea : e0];
        sb = csr_src[eb < e1 ? eb : e0];
    }
    for (int e = e0; e < e1; e += 8) {
        bool va = (e + slot) < e1, vb = (e + 4 + slot) < e1;
        bf16x8 xua = *(const bf16x8*)(xlr + (size_t)sa * 256 + cl);
        bf16x8 xub = *(const bf16x8*)(xlr + (size_t)sb * 256 + cl);
        // prefetch next iteration's CSR indices; overlaps the compute below
        {
            int ea2 = e + 8 + slot, eb2 = e + 12 + slot;
            sa = csr_src[ea2 < e1 ? ea2 : e0];
            sb = csr_src[eb2 < e1 ? eb2 : e0];
        }
        float xa[8], xb[8];
        #pragma unroll
        for (int j = 0; j < 8; ++j) { xa[j] = bf2f((ushort_t)xua[j]); xb[j] = bf2f((ushort_t)xub[j]); }
        float pa = 0.f, qa = 0.f, pb = 0.f, qb = 0.f;
        #pragma unroll
        for (int j = 0; j < 8; ++j) {
            float sva = xa[j] + xr[j];
            float svb = xb[j] + xr[j];
            pa = fmaf(at4[j], fabsf(sva), pa);   // abs is a free VOP3 modifier
            qa = fmaf(at4[j], xa[j], qa);
            pb = fmaf(at4[j], fabsf(svb), pb);
            qb = fmaf(at4[j], xb[j], qb);
        }
        float ta = fmaf(1.5f, qa, pa);           // log2e*(pa_e + 1.5 qa_e)
        float tb = fmaf(1.5f, qb, pb);
        ta += __shfl_xor(ta, 1); ta += __shfl_xor(ta, 2);
        tb += __shfl_xor(tb, 1); tb += __shfl_xor(tb, 2);
        float aa = va ? exp2f(ta) : 0.f;
        float ab = vb ? exp2f(tb) : 0.f;
        suma += aa + ab;
        #pragma unroll
        for (int j = 0; j < 8; ++j) acc[j] = fmaf(aa, xa[j], fmaf(ab, xb[j], acc[j]));
    }
    // combine the four edge slots
    suma += __shfl_xor(suma, 16); suma += __shfl_xor(suma, 32);
    #pragma unroll
    for (int j = 0; j < 8; ++j) {
        acc[j] += __shfl_xor(acc[j], 16);
        acc[j] += __shfl_xor(acc[j], 32);
    }
    if (slot == 0) {
        float inv = 1.0f / (suma + 1e-16f);
        float4 ob0 = *(const float4*)(b_out + cl);
        float4 ob1 = *(const float4*)(b_out + cl + 4);
        float ob[8] = {ob0.x, ob0.y, ob0.z, ob0.w, ob1.x, ob1.y, ob1.z, ob1.w};
        short r[8];
        #pragma unroll
        for (int j = 0; j < 8; ++j) r[j] = f2bf(fmaf(acc[j], inv, ob[j]));
        *(bf16x8*)(g + (size_t)node * 128 + cl) = *(const bf16x8*)r;
    }
}

// ---------------- PairNorm column sums (bf16 g), vectorized bf16x8 loads -----------
// thread (tid&15) owns channel block, (tid>>4) the row phase; 256-row window/block.
__global__ __launch_bounds__(256, 8)
void colsum_k(const ushort_t* __restrict__ g, float* __restrict__ colsum) {
    __shared__ float buf[16][128];
    int c8 = (threadIdx.x & 15) << 3;
    int rg = threadIdx.x >> 4;                   // 0..15
    int r0 = blockIdx.x * 256;
    float s[8] = {0.f,0.f,0.f,0.f,0.f,0.f,0.f,0.f};
    #pragma unroll 4
    for (int it = 0; it < 16; ++it) {
        int r = r0 + rg + (it << 4);
        if (r < NN) {
            bf16x8 v = *(const bf16x8*)(g + (size_t)r * 128 + c8);
            #pragma unroll
            for (int j = 0; j < 8; ++j) s[j] += bf2f((ushort_t)v[j]);
        }
    }
    #pragma unroll
    for (int j = 0; j < 8; ++j) buf[rg][c8 + j] = s[j];
    __syncthreads();
    if (threadIdx.x < 128) {
        float t = 0.f;
        #pragma unroll
        for (int k = 0; k < 16; ++k) t += buf[k][threadIdx.x];
        atomicAdd(&colsum[threadIdx.x], t);
    }
}

// ---------------- fused pairnorm + residual + layernorm (+relu) --------------------
// 4 nodes per wave: 16 lanes x 8 channels each (bf16x8 loads), shuffle reduces
// within the 16-lane group (masks 1,2,4,8).
__global__ __launch_bounds__(256, 8)
void finalize_k(const ushort_t* __restrict__ g, const float* __restrict__ colsum,
                const ushort_t* __restrict__ ident, const float* __restrict__ lng,
                const float* __restrict__ lnb, ushort_t* __restrict__ hout_bf,
                float* __restrict__ hout_f32, int is_final)
{
    int lane = threadIdx.x & 63;
    int li   = lane & 15;
    int node = blockIdx.x * 16 + ((threadIdx.x >> 6) << 2) + (lane >> 4);
    int c8   = li << 3;
    const float invN = 1.0f / (float)NN;
    const float sqrtN = sqrtf((float)NN);

    bf16x8 vu = *(const bf16x8*)(g + (size_t)node * 128 + c8);
    float4 cs0 = *(const float4*)(colsum + c8);
    float4 cs1 = *(const float4*)(colsum + c8 + 4);
    float cs[8] = {cs0.x, cs0.y, cs0.z, cs0.w, cs1.x, cs1.y, cs1.z, cs1.w};
    float x[8], ss = 0.f;
    #pragma unroll
    for (int j = 0; j < 8; ++j) {
        x[j] = bf2f((ushort_t)vu[j]) - cs[j] * invN;
        ss = fmaf(x[j], x[j], ss);
    }
    ss += __shfl_xor(ss, 1); ss += __shfl_xor(ss, 2);
    ss += __shfl_xor(ss, 4); ss += __shfl_xor(ss, 8);
    float sc = sqrtN / (sqrtf(ss) + 1e-6f);

    bf16x8 idu = *(const bf16x8*)(ident + (size_t)node * 128 + c8);
    float t[8], m = 0.f;
    #pragma unroll
    for (int j = 0; j < 8; ++j) {
        t[j] = fmaf(x[j], sc, bf2f((ushort_t)idu[j]));
        m += t[j];
    }
    m += __shfl_xor(m, 1); m += __shfl_xor(m, 2);
    m += __shfl_xor(m, 4); m += __shfl_xor(m, 8);
    m *= (1.0f / 128.0f);
    float d[8], vv = 0.f;
    #pragma unroll
    for (int j = 0; j < 8; ++j) { d[j] = t[j] - m; vv = fmaf(d[j], d[j], vv); }
    vv += __shfl_xor(vv, 1); vv += __shfl_xor(vv, 2);
    vv += __shfl_xor(vv, 4); vv += __shfl_xor(vv, 8);
    vv *= (1.0f / 128.0f);
    float r = rsqrtf(vv + 1e-5f);

    float4 lg0 = *(const float4*)(lng + c8);
    float4 lg1 = *(const float4*)(lng + c8 + 4);
    float4 lb0 = *(const float4*)(lnb + c8);
    float4 lb1 = *(const float4*)(lnb + c8 + 4);
    float lg[8] = {lg0.x, lg0.y, lg0.z, lg0.w, lg1.x, lg1.y, lg1.z, lg1.w};
    float lb[8] = {lb0.x, lb0.y, lb0.z, lb0.w, lb1.x, lb1.y, lb1.z, lb1.w};

    if (is_final) {
        float y[8];
        #pragma unroll
        for (int j = 0; j < 8; ++j) y[j] = fmaf(d[j] * r, lg[j], lb[j]);
        float* op = hout_f32 + (size_t)node * 128 + c8;
        float4 o0, o1;
        o0.x=y[0]; o0.y=y[1]; o0.z=y[2]; o0.w=y[3];
        o1.x=y[4]; o1.y=y[5]; o1.z=y[6]; o1.w=y[7];
        *(float4*)op = o0; *(float4*)(op + 4) = o1;
    } else {
        short o[8];
        #pragma unroll
        for (int j = 0; j < 8; ++j) {
            float y = fmaf(d[j] * r, lg[j], lb[j]);
            o[j] = f2bf(fmaxf(y, 0.f));
        }
        *(bf16x8*)(hout_bf + (size_t)node * 128 + c8) = *(const bf16x8*)o;
    }
}

// ---------------- host launch ----------------
extern "C" void kernel_launch(void* const* d_in, const int* in_sizes, int n_in,
                              void* d_out, int out_size, void* d_ws, size_t ws_size,
                              hipStream_t stream) {
    const float* x     = (const float*)d_in[0];
    const int*   ei    = (const int*)  d_in[1];   // [2][E]
    const float* w_in  = (const float*)d_in[2];
    const float* b_in  = (const float*)d_in[3];
    const float* Wl    = (const float*)d_in[4];
    const float* bl    = (const float*)d_in[5];
    const float* Wr    = (const float*)d_in[6];
    const float* att   = (const float*)d_in[7];
    const float* b_out = (const float*)d_in[8];
    const float* Wres  = (const float*)d_in[9];
    const float* bres  = (const float*)d_in[10];
    const float* ln_g  = (const float*)d_in[11];
    const float* ln_b  = (const float*)d_in[12];

    // workspace layout (bf16 feature buffers)
    ushort_t* h     = (ushort_t*)d_ws;                 // N*128 bf16
    ushort_t* xlr   = h + (size_t)NN * 128;            // N*256 bf16
    ushort_t* ident = xlr + (size_t)NN * 256;          // N*128 bf16
    ushort_t* g     = ident + (size_t)NN * 128;        // N*128 bf16
    ushort_t* wt    = g + (size_t)NN * 128;            // 9*128*128 bf16 (transposed weights)
    int*   row_ptr = (int*)(wt + 9 * 16384);           // N+1
    int*   cursor  = row_ptr + (NN + 1);               // N     (zeroed; also deg)
    float* colsum  = (float*)(cursor + NN);            // 3*128 (zeroed)
    int*   bsum    = (int*)(colsum + 384);             // 512
    int*   csr_src = bsum + 512;                       // E

    const int* e_src = ei;
    const int* e_dst = ei + NE;

    hipMemsetAsync(cursor, 0, (size_t)(NN + 384) * 4, stream);

    // weight transpose prep (once per call)
    prep_w_k<<<dim3(4, 4, 9), dim3(32, 8), 0, stream>>>(w_in, Wl, Wr, Wres, wt);

    // CSR build
    const int nb = (NN + 255) / 256;             // 391
    count_k  <<<NE / 256, 256, 0, stream>>>(e_dst, cursor);
    scan1_k  <<<nb, 256, 0, stream>>>(cursor, row_ptr, bsum);
    scan2_k  <<<1, 512, 0, stream>>>(bsum, nb, row_ptr + NN);
    scan3_k  <<<nb, 256, 0, stream>>>(row_ptr, bsum, cursor);
    scatter_k<<<NE / 256, 256, 0, stream>>>(e_src, e_dst, cursor, csr_src);

    const int gx = (NN + 127) / 128;             // 782

    // h = bf16(x @ w_in + b_in)
    gemm_k<1><<<dim3(gx, 1), 256, 0, stream>>>(x, wt, 0, 0, 0,
                                               b_in, nullptr, h, 128, nullptr, NN);

    for (int i = 0; i < 3; ++i) {
        // xlr = bf16(h @ [Wl | Wr] + [bl | 0]); (i>0) ident = bf16(h @ Wres + bres)
        gemm_k<0><<<dim3(gx, (i > 0) ? 3 : 2), 256, 0, stream>>>(
            h, wt, 1 + i, 4 + i, 7 + (i - 1),
            bl + i * 128, (i > 0) ? (bres + (i - 1) * 128) : nullptr,
            xlr, 256, ident, NN);
        gat_aggregate_k<<<NN / 4, 256, 0, stream>>>(xlr, row_ptr, csr_src,
                                                    att + i * 128, b_out + i * 128, g);
        colsum_k<<<nb, 256, 0, stream>>>(g, colsum + i * 128);
        finalize_k<<<NN / 16, 256, 0, stream>>>(g, colsum + i * 128,
                                                (i == 0) ? h : ident,
                                                ln_g + i * 128, ln_b + i * 128,
                                                h, (float*)d_out, (i == 2) ? 1 : 0);
    }
}

// Round 11
// 554.336 us; speedup vs baseline: 1.0527x; 1.0527x over previous
//
#include <hip/hip_runtime.h>
#include <hip/hip_bf16.h>

#define NN 100000
#define NE 800000
// D=128, H=4, C=32

typedef __attribute__((ext_vector_type(8))) short bf16x8;
typedef __attribute__((ext_vector_type(4))) float f32x4;
typedef unsigned short ushort_t;

static __device__ __forceinline__ short f2bf(float f) {
    union { float f; unsigned u; } v; v.f = f;
    unsigned u = v.u;
    unsigned r = u + 0x7FFFu + ((u >> 16) & 1u);   // RNE
    return (short)(r >> 16);
}
static __device__ __forceinline__ float bf2f(unsigned short u) {
    union { unsigned u; float f; } v; v.u = ((unsigned)u) << 16;
    return v.f;
}

// ---------------- weight prep: W[k][c] fp32 -> Wt[c][k] bf16, 9 matrices ------------
__global__ void prep_w_k(const float* __restrict__ w_in, const float* __restrict__ Wl,
                         const float* __restrict__ Wr, const float* __restrict__ Wres,
                         ushort_t* __restrict__ wt)
{
    __shared__ float tile[32][33];
    int m = blockIdx.z;
    const float* src;
    if (m == 0)      src = w_in;
    else if (m < 4)  src = Wl + (size_t)(m - 1) * 16384;
    else if (m < 7)  src = Wr + (size_t)(m - 4) * 16384;
    else             src = Wres + (size_t)(m - 7) * 16384;
    ushort_t* dst = wt + (size_t)m * 16384;

    int tx = threadIdx.x, ty = threadIdx.y;
    int k0 = blockIdx.x * 32, c0 = blockIdx.y * 32;
    #pragma unroll
    for (int j = 0; j < 4; ++j)
        tile[ty + 8 * j][tx] = src[(size_t)(k0 + ty + 8 * j) * 128 + c0 + tx];
    __syncthreads();
    #pragma unroll
    for (int j = 0; j < 4; ++j)
        dst[(size_t)(c0 + ty + 8 * j) * 128 + k0 + tx] = (ushort_t)f2bf(tile[tx][ty + 8 * j]);
}

// ---------------- GEMM: 128-row tiles, B-tile staged dense in LDS ----------------
// out = A[M x 128] @ wt[w_y]^T + bias; y-slices run concurrently sharing A via L2.
// Hybrid epilogue (R10 post-mortem): operand-swapped MFMA (verified R10: lane holds
// out[row=..+lr][cols = nt*16+quad*4 .. +3], 4 CONSECUTIVE cols) -> bias + 2x
// v_cvt_pk_bf16_f32 + one ds_write_b64 per (mt,nt) into the C-tile, then the R9
// coalesced 16B/lane readback+store. Replaces R9's 64 scalar f2bf+ds_write_u16
// (~400 instr -> ~170) while keeping fully-coalesced global stores (R10's direct
// 8B scattered stores cost more than they saved).
template<int A_FP32>
__global__ __launch_bounds__(256, 4)
void gemm_k(const void* __restrict__ Av, const ushort_t* __restrict__ wt,
            int w0, int w1, int w2,
            const float* __restrict__ bias0, const float* __restrict__ bias2,
            ushort_t* __restrict__ out0, int Dout0, ushort_t* __restrict__ out2, int M)
{
    __shared__ short Bs[128][136];   // B-tile [col][k]; reused as C-tile [row][col]
    const int tid = threadIdx.x;
    const int rowBlk = blockIdx.x * 128;
    const int y = blockIdx.y;
    const ushort_t* W = wt + (size_t)((y == 0) ? w0 : (y == 1) ? w1 : w2) * 16384;
    const float* bias = (y == 0) ? bias0 : ((y == 2) ? bias2 : nullptr);
    ushort_t* out = (y == 2) ? out2 : out0;
    const int Dout   = (y == 2) ? 128 : Dout0;
    const int colOff = (y == 1) ? 128 : 0;

    const int wave = tid >> 6;
    const int lane = tid & 63;
    const int quad = lane >> 4;
    const int lr   = lane & 15;

    const int row0 = rowBlk + wave * 32 + lr;       // A fragment rows
    const int row1 = row0 + 16;

    // ---- A fragments direct from global (issued first, latency-hidden) ----
    bf16x8 afr[4][2];
    #pragma unroll
    for (int ks = 0; ks < 4; ++ks) {
        int kb = ks * 32 + quad * 8;
        bf16x8 a0 = (bf16x8)0, a1 = (bf16x8)0;
        if (A_FP32) {
            const float* A = (const float*)Av;
            if (row0 < M) {
                float4 v0 = *(const float4*)(A + (size_t)row0 * 128 + kb);
                float4 v1 = *(const float4*)(A + (size_t)row0 * 128 + kb + 4);
                a0[0]=f2bf(v0.x); a0[1]=f2bf(v0.y); a0[2]=f2bf(v0.z); a0[3]=f2bf(v0.w);
                a0[4]=f2bf(v1.x); a0[5]=f2bf(v1.y); a0[6]=f2bf(v1.z); a0[7]=f2bf(v1.w);
            }
            if (row1 < M) {
                float4 v0 = *(const float4*)(A + (size_t)row1 * 128 + kb);
                float4 v1 = *(const float4*)(A + (size_t)row1 * 128 + kb + 4);
                a1[0]=f2bf(v0.x); a1[1]=f2bf(v0.y); a1[2]=f2bf(v0.z); a1[3]=f2bf(v0.w);
                a1[4]=f2bf(v1.x); a1[5]=f2bf(v1.y); a1[6]=f2bf(v1.z); a1[7]=f2bf(v1.w);
            }
        } else {
            const ushort_t* A = (const ushort_t*)Av;
            if (row0 < M) a0 = *(const bf16x8*)(A + (size_t)row0 * 128 + kb);
            if (row1 < M) a1 = *(const bf16x8*)(A + (size_t)row1 * 128 + kb);
        }
        afr[ks][0] = a0; afr[ks][1] = a1;
    }

    // ---- stage B-tile densely: global 16B/lane contiguous -> LDS rows ----
    #pragma unroll
    for (int i = 0; i < 8; ++i) {
        int linear = tid + 256 * i;              // 2048 16B chunks
        int r  = linear >> 4;
        int c8 = (linear & 15) << 3;
        *(bf16x8*)&Bs[r][c8] = *(const bf16x8*)(W + (size_t)r * 128 + c8);
    }
    __syncthreads();

    f32x4 acc[2][8];
    #pragma unroll
    for (int mt = 0; mt < 2; ++mt)
        #pragma unroll
        for (int nt = 0; nt < 8; ++nt) acc[mt][nt] = (f32x4)(0.0f);

    #pragma unroll
    for (int ks = 0; ks < 4; ++ks) {
        int kb = ks * 32 + quad * 8;
        #pragma unroll
        for (int nt = 0; nt < 8; ++nt) {
            bf16x8 b = *(const bf16x8*)&Bs[nt * 16 + lr][kb];
            // swapped operands (verified R10): lane holds
            // out[row = ...+lr][col = nt*16 + quad*4 + reg]
            acc[0][nt] = __builtin_amdgcn_mfma_f32_16x16x32_bf16(b, afr[ks][0], acc[0][nt], 0, 0, 0);
            acc[1][nt] = __builtin_amdgcn_mfma_f32_16x16x32_bf16(b, afr[ks][1], acc[1][nt], 0, 0, 0);
        }
    }

    // ---- epilogue: packed 8B writes into C-tile, then coalesced readback+store ----
    __syncthreads();                             // all waves done reading B
    #pragma unroll
    for (int nt = 0; nt < 8; ++nt) {
        int colBase = nt * 16 + quad * 4;
        float4 bv;
        if (bias) bv = *(const float4*)(bias + colBase);
        else { bv.x = 0.f; bv.y = 0.f; bv.z = 0.f; bv.w = 0.f; }
        #pragma unroll
        for (int mt = 0; mt < 2; ++mt) {
            int row = wave * 32 + mt * 16 + lr;
            float y0 = acc[mt][nt][0] + bv.x, y1 = acc[mt][nt][1] + bv.y;
            float y2 = acc[mt][nt][2] + bv.z, y3 = acc[mt][nt][3] + bv.w;
            unsigned lo, hi;
            asm("v_cvt_pk_bf16_f32 %0, %1, %2" : "=v"(lo) : "v"(y0), "v"(y1));
            asm("v_cvt_pk_bf16_f32 %0, %1, %2" : "=v"(hi) : "v"(y2), "v"(y3));
            uint2 o; o.x = lo; o.y = hi;
            *(uint2*)&Bs[row][colBase] = o;      // 8B-aligned: colBase*2 % 8 == 0, 272B row stride
        }
    }
    __syncthreads();
    #pragma unroll
    for (int i = 0; i < 8; ++i) {
        int linear = tid + 256 * i;              // 2048 16B chunks
        int r  = linear >> 4;
        int c8 = (linear & 15) << 3;
        int gr = rowBlk + r;
        if (gr < M)
            *(bf16x8*)(out + (size_t)gr * Dout + colOff + c8) = *(const bf16x8*)&Bs[r][c8];
    }
}

// ---------------- CSR build ----------------
__global__ void count_k(const int* __restrict__ dst, int* __restrict__ deg) {
    int e = blockIdx.x * 256 + threadIdx.x;
    if (e < NE) atomicAdd(&deg[dst[e]], 1);
}

__global__ void scan1_k(const int* __restrict__ deg, int* __restrict__ excl,
                        int* __restrict__ bsum) {
    __shared__ int buf[256];
    int i = blockIdx.x * 256 + threadIdx.x;
    int v = (i < NN) ? deg[i] : 0;
    buf[threadIdx.x] = v; __syncthreads();
    for (int off = 1; off < 256; off <<= 1) {
        int t = (threadIdx.x >= off) ? buf[threadIdx.x - off] : 0;
        __syncthreads();
        buf[threadIdx.x] += t;
        __syncthreads();
    }
    if (i < NN) excl[i] = buf[threadIdx.x] - v;
    if (threadIdx.x == 255) bsum[blockIdx.x] = buf[255];
}

__global__ void scan2_k(int* __restrict__ bsum, int nb, int* __restrict__ total) {
    __shared__ int buf[512];
    int v = (threadIdx.x < nb) ? bsum[threadIdx.x] : 0;
    buf[threadIdx.x] = v; __syncthreads();
    for (int off = 1; off < 512; off <<= 1) {
        int t = (threadIdx.x >= off) ? buf[threadIdx.x - off] : 0;
        __syncthreads();
        buf[threadIdx.x] += t;
        __syncthreads();
    }
    if (threadIdx.x < nb) bsum[threadIdx.x] = buf[threadIdx.x] - v;  // exclusive base
    if (threadIdx.x == 511) *total = buf[511];
}

__global__ void scan3_k(int* __restrict__ row_ptr, const int* __restrict__ bsum,
                        int* __restrict__ cursor) {
    int i = blockIdx.x * 256 + threadIdx.x;
    if (i < NN) {
        int v = row_ptr[i] + bsum[blockIdx.x];
        row_ptr[i] = v;
        cursor[i]  = v;
    }
}

__global__ void scatter_k(const int* __restrict__ src, const int* __restrict__ dst,
                          int* __restrict__ cursor, int* __restrict__ csr_src) {
    int e = blockIdx.x * 256 + threadIdx.x;
    if (e < NE) {
        int p = atomicAdd(&cursor[dst[e]], 1);
        csr_src[p] = src[e];
    }
}

// ---------------- GATv2 aggregate: one wave per destination node, 8 edges/iter --------
// R9 form (best measured): prefetched csr indices, abs-decomposed logit in log2 domain.
__global__ __launch_bounds__(256, 8)
void gat_aggregate_k(const ushort_t* __restrict__ xlr, const int* __restrict__ row_ptr,
                     const int* __restrict__ csr_src, const float* __restrict__ att,
                     const float* __restrict__ b_out, ushort_t* __restrict__ g)
{
    int node = blockIdx.x * 4 + (threadIdx.x >> 6);
    int lane = threadIdx.x & 63;
    int slot = lane >> 4;
    int cl   = (lane & 15) << 3;                 // channels cl..cl+7
    bf16x8 xru = *(const bf16x8*)(xlr + (size_t)node * 256 + 128 + cl);
    float xr[8], at4[8];
    #pragma unroll
    for (int j = 0; j < 8; ++j) xr[j] = bf2f((ushort_t)xru[j]);
    const float k4 = 0.4f * 1.44269504f;         // 0.4 * log2(e)
    float4 at0 = *(const float4*)(att + cl);
    float4 at1 = *(const float4*)(att + cl + 4);
    at4[0] = k4*at0.x; at4[1] = k4*at0.y; at4[2] = k4*at0.z; at4[3] = k4*at0.w;
    at4[4] = k4*at1.x; at4[5] = k4*at1.y; at4[6] = k4*at1.z; at4[7] = k4*at1.w;

    int e0 = row_ptr[node], e1 = row_ptr[node + 1];
    float acc[8] = {0.f,0.f,0.f,0.f,0.f,0.f,0.f,0.f};
    float suma = 0.f;

    // prime the index pipeline (guard deg==0 nodes: never read past csr_src[e1-1])
    int sa = 0, sb = 0;
    if (e0 < e1) {
        int ea = e0 + slot, eb = e0 + 4 + slot;
        sa = csr_src[ea < e1 ? ea : e0];
        sb = csr_src[eb < e1 ? eb : e0];
    }
    for (int e = e0; e < e1; e += 8) {
        bool va = (e + slot) < e1, vb = (e + 4 + slot) < e1;
        bf16x8 xua = *(const bf16x8*)(xlr + (size_t)sa * 256 + cl);
        bf16x8 xub = *(const bf16x8*)(xlr + (size_t)sb * 256 + cl);
        // prefetch next iteration's CSR indices; overlaps the compute below
        {
            int ea2 = e + 8 + slot, eb2 = e + 12 + slot;
            sa = csr_src[ea2 < e1 ? ea2 : e0];
            sb = csr_src[eb2 < e1 ? eb2 : e0];
        }
        float xa[8], xb[8];
        #pragma unroll
        for (int j = 0; j < 8; ++j) { xa[j] = bf2f((ushort_t)xua[j]); xb[j] = bf2f((ushort_t)xub[j]); }
        float pa = 0.f, qa = 0.f, pb = 0.f, qb = 0.f;
        #pragma unroll
        for (int j = 0; j < 8; ++j) {
            float sva = xa[j] + xr[j];
            float svb = xb[j] + xr[j];
            pa = fmaf(at4[j], fabsf(sva), pa);   // abs is a free VOP3 modifier
            qa = fmaf(at4[j], xa[j], qa);
            pb = fmaf(at4[j], fabsf(svb), pb);
            qb = fmaf(at4[j], xb[j], qb);
        }
        float ta = fmaf(1.5f, qa, pa);           // log2e*(pa_e + 1.5 qa_e)
        float tb = fmaf(1.5f, qb, pb);
        ta += __shfl_xor(ta, 1); ta += __shfl_xor(ta, 2);
        tb += __shfl_xor(tb, 1); tb += __shfl_xor(tb, 2);
        float aa = va ? exp2f(ta) : 0.f;
        float ab = vb ? exp2f(tb) : 0.f;
        suma += aa + ab;
        #pragma unroll
        for (int j = 0; j < 8; ++j) acc[j] = fmaf(aa, xa[j], fmaf(ab, xb[j], acc[j]));
    }
    // combine the four edge slots
    suma += __shfl_xor(suma, 16); suma += __shfl_xor(suma, 32);
    #pragma unroll
    for (int j = 0; j < 8; ++j) {
        acc[j] += __shfl_xor(acc[j], 16);
        acc[j] += __shfl_xor(acc[j], 32);
    }
    if (slot == 0) {
        float inv = 1.0f / (suma + 1e-16f);
        float4 ob0 = *(const float4*)(b_out + cl);
        float4 ob1 = *(const float4*)(b_out + cl + 4);
        float ob[8] = {ob0.x, ob0.y, ob0.z, ob0.w, ob1.x, ob1.y, ob1.z, ob1.w};
        short r[8];
        #pragma unroll
        for (int j = 0; j < 8; ++j) r[j] = f2bf(fmaf(acc[j], inv, ob[j]));
        *(bf16x8*)(g + (size_t)node * 128 + cl) = *(const bf16x8*)r;
    }
}

// ---------------- PairNorm column sums (bf16 g), vectorized bf16x8 loads -----------
// thread (tid&15) owns channel block, (tid>>4) the row phase; 256-row window/block.
__global__ __launch_bounds__(256, 8)
void colsum_k(const ushort_t* __restrict__ g, float* __restrict__ colsum) {
    __shared__ float buf[16][128];
    int c8 = (threadIdx.x & 15) << 3;
    int rg = threadIdx.x >> 4;                   // 0..15
    int r0 = blockIdx.x * 256;
    float s[8] = {0.f,0.f,0.f,0.f,0.f,0.f,0.f,0.f};
    #pragma unroll 4
    for (int it = 0; it < 16; ++it) {
        int r = r0 + rg + (it << 4);
        if (r < NN) {
            bf16x8 v = *(const bf16x8*)(g + (size_t)r * 128 + c8);
            #pragma unroll
            for (int j = 0; j < 8; ++j) s[j] += bf2f((ushort_t)v[j]);
        }
    }
    #pragma unroll
    for (int j = 0; j < 8; ++j) buf[rg][c8 + j] = s[j];
    __syncthreads();
    if (threadIdx.x < 128) {
        float t = 0.f;
        #pragma unroll
        for (int k = 0; k < 16; ++k) t += buf[k][threadIdx.x];
        atomicAdd(&colsum[threadIdx.x], t);
    }
}

// ---------------- fused pairnorm + residual + layernorm (+relu) --------------------
// 4 nodes per wave: 16 lanes x 8 channels each (bf16x8 loads), shuffle reduces
// within the 16-lane group (masks 1,2,4,8).
__global__ __launch_bounds__(256, 8)
void finalize_k(const ushort_t* __restrict__ g, const float* __restrict__ colsum,
                const ushort_t* __restrict__ ident, const float* __restrict__ lng,
                const float* __restrict__ lnb, ushort_t* __restrict__ hout_bf,
                float* __restrict__ hout_f32, int is_final)
{
    int lane = threadIdx.x & 63;
    int li   = lane & 15;
    int node = blockIdx.x * 16 + ((threadIdx.x >> 6) << 2) + (lane >> 4);
    int c8   = li << 3;
    const float invN = 1.0f / (float)NN;
    const float sqrtN = sqrtf((float)NN);

    bf16x8 vu = *(const bf16x8*)(g + (size_t)node * 128 + c8);
    float4 cs0 = *(const float4*)(colsum + c8);
    float4 cs1 = *(const float4*)(colsum + c8 + 4);
    float cs[8] = {cs0.x, cs0.y, cs0.z, cs0.w, cs1.x, cs1.y, cs1.z, cs1.w};
    float x[8], ss = 0.f;
    #pragma unroll
    for (int j = 0; j < 8; ++j) {
        x[j] = bf2f((ushort_t)vu[j]) - cs[j] * invN;
        ss = fmaf(x[j], x[j], ss);
    }
    ss += __shfl_xor(ss, 1); ss += __shfl_xor(ss, 2);
    ss += __shfl_xor(ss, 4); ss += __shfl_xor(ss, 8);
    float sc = sqrtN / (sqrtf(ss) + 1e-6f);

    bf16x8 idu = *(const bf16x8*)(ident + (size_t)node * 128 + c8);
    float t[8], m = 0.f;
    #pragma unroll
    for (int j = 0; j < 8; ++j) {
        t[j] = fmaf(x[j], sc, bf2f((ushort_t)idu[j]));
        m += t[j];
    }
    m += __shfl_xor(m, 1); m += __shfl_xor(m, 2);
    m += __shfl_xor(m, 4); m += __shfl_xor(m, 8);
    m *= (1.0f / 128.0f);
    float d[8], vv = 0.f;
    #pragma unroll
    for (int j = 0; j < 8; ++j) { d[j] = t[j] - m; vv = fmaf(d[j], d[j], vv); }
    vv += __shfl_xor(vv, 1); vv += __shfl_xor(vv, 2);
    vv += __shfl_xor(vv, 4); vv += __shfl_xor(vv, 8);
    vv *= (1.0f / 128.0f);
    float r = rsqrtf(vv + 1e-5f);

    float4 lg0 = *(const float4*)(lng + c8);
    float4 lg1 = *(const float4*)(lng + c8 + 4);
    float4 lb0 = *(const float4*)(lnb + c8);
    float4 lb1 = *(const float4*)(lnb + c8 + 4);
    float lg[8] = {lg0.x, lg0.y, lg0.z, lg0.w, lg1.x, lg1.y, lg1.z, lg1.w};
    float lb[8] = {lb0.x, lb0.y, lb0.z, lb0.w, lb1.x, lb1.y, lb1.z, lb1.w};

    if (is_final) {
        float y[8];
        #pragma unroll
        for (int j = 0; j < 8; ++j) y[j] = fmaf(d[j] * r, lg[j], lb[j]);
        float* op = hout_f32 + (size_t)node * 128 + c8;
        float4 o0, o1;
        o0.x=y[0]; o0.y=y[1]; o0.z=y[2]; o0.w=y[3];
        o1.x=y[4]; o1.y=y[5]; o1.z=y[6]; o1.w=y[7];
        *(float4*)op = o0; *(float4*)(op + 4) = o1;
    } else {
        short o[8];
        #pragma unroll
        for (int j = 0; j < 8; ++j) {
            float y = fmaf(d[j] * r, lg[j], lb[j]);
            o[j] = f2bf(fmaxf(y, 0.f));
        }
        *(bf16x8*)(hout_bf + (size_t)node * 128 + c8) = *(const bf16x8*)o;
    }
}

// ---------------- host launch ----------------
extern "C" void kernel_launch(void* const* d_in, const int* in_sizes, int n_in,
                              void* d_out, int out_size, void* d_ws, size_t ws_size,
                              hipStream_t stream) {
    const float* x     = (const float*)d_in[0];
    const int*   ei    = (const int*)  d_in[1];   // [2][E]
    const float* w_in  = (const float*)d_in[2];
    const float* b_in  = (const float*)d_in[3];
    const float* Wl    = (const float*)d_in[4];
    const float* bl    = (const float*)d_in[5];
    const float* Wr    = (const float*)d_in[6];
    const float* att   = (const float*)d_in[7];
    const float* b_out = (const float*)d_in[8];
    const float* Wres  = (const float*)d_in[9];
    const float* bres  = (const float*)d_in[10];
    const float* ln_g  = (const float*)d_in[11];
    const float* ln_b  = (const float*)d_in[12];

    // workspace layout (bf16 feature buffers)
    ushort_t* h     = (ushort_t*)d_ws;                 // N*128 bf16
    ushort_t* xlr   = h + (size_t)NN * 128;            // N*256 bf16
    ushort_t* ident = xlr + (size_t)NN * 256;          // N*128 bf16
    ushort_t* g     = ident + (size_t)NN * 128;        // N*128 bf16
    ushort_t* wt    = g + (size_t)NN * 128;            // 9*128*128 bf16 (transposed weights)
    int*   row_ptr = (int*)(wt + 9 * 16384);           // N+1
    int*   cursor  = row_ptr + (NN + 1);               // N     (zeroed; also deg)
    float* colsum  = (float*)(cursor + NN);            // 3*128 (zeroed)
    int*   bsum    = (int*)(colsum + 384);             // 512
    int*   csr_src = bsum + 512;                       // E

    const int* e_src = ei;
    const int* e_dst = ei + NE;

    hipMemsetAsync(cursor, 0, (size_t)(NN + 384) * 4, stream);

    // weight transpose prep (once per call)
    prep_w_k<<<dim3(4, 4, 9), dim3(32, 8), 0, stream>>>(w_in, Wl, Wr, Wres, wt);

    // CSR build
    const int nb = (NN + 255) / 256;             // 391
    count_k  <<<NE / 256, 256, 0, stream>>>(e_dst, cursor);
    scan1_k  <<<nb, 256, 0, stream>>>(cursor, row_ptr, bsum);
    scan2_k  <<<1, 512, 0, stream>>>(bsum, nb, row_ptr + NN);
    scan3_k  <<<nb, 256, 0, stream>>>(row_ptr, bsum, cursor);
    scatter_k<<<NE / 256, 256, 0, stream>>>(e_src, e_dst, cursor, csr_src);

    const int gx = (NN + 127) / 128;             // 782

    // h = bf16(x @ w_in + b_in)
    gemm_k<1><<<dim3(gx, 1), 256, 0, stream>>>(x, wt, 0, 0, 0,
                                               b_in, nullptr, h, 128, nullptr, NN);

    for (int i = 0; i < 3; ++i) {
        // xlr = bf16(h @ [Wl | Wr] + [bl | 0]); (i>0) ident = bf16(h @ Wres + bres)
        gemm_k<0><<<dim3(gx, (i > 0) ? 3 : 2), 256, 0, stream>>>(
            h, wt, 1 + i, 4 + i, 7 + (i - 1),
            bl + i * 128, (i > 0) ? (bres + (i - 1) * 128) : nullptr,
            xlr, 256, ident, NN);
        gat_aggregate_k<<<NN / 4, 256, 0, stream>>>(xlr, row_ptr, csr_src,
                                                    att + i * 128, b_out + i * 128, g);
        colsum_k<<<nb, 256, 0, stream>>>(g, colsum + i * 128);
        finalize_k<<<NN / 16, 256, 0, stream>>>(g, colsum + i * 128,
                                                (i == 0) ? h : ident,
                                                ln_g + i * 128, ln_b + i * 128,
                                                h, (float*)d_out, (i == 2) ? 1 : 0);
    }
}